// Round 1
// baseline (207.646 us; speedup 1.0000x reference)
//
#include <hip/hip_runtime.h>

// Problem constants (fixed by setup_inputs)
#define U   128
#define TN  (256 * 1024)          // T*N elements in final output
#define TN4 (TN / 4)              // float4 granularity

// ws layout (floats): [0] = sum(final), [1] = sum(input_spikes), [2..129] = w[j]

__global__ __launch_bounds__(128) void prep_kernel(const float* __restrict__ conn,
                                                   float* __restrict__ ws) {
    int j = threadIdx.x;              // 0..127
    if (j < 2) ws[j] = 0.0f;          // zero the accumulators (ws is poisoned 0xAA)
    float s = 0.0f;
#pragma unroll 8
    for (int i = 0; i < U; ++i) {
        float c = conn[i * U + j];
        s += (c > 0.1f) ? c : 0.0f;
    }
    ws[2 + j] = 3.0f * s;
}

__global__ __launch_bounds__(256) void main_kernel(const float4* __restrict__ uo,   // [U][TN4]
                                                   const float4* __restrict__ tgt,  // [TN4]
                                                   const float4* __restrict__ insp, // [TN4]
                                                   float4* __restrict__ out,        // [TN4]
                                                   float* __restrict__ ws) {
    __shared__ float w_s[U];
    int tid = threadIdx.x;
    if (tid < U) w_s[tid] = ws[2 + tid];
    __syncthreads();

    int idx = blockIdx.x * 256 + tid;     // 0..TN4-1
    const float4* p = uo + idx;

    float4 acc = make_float4(0.f, 0.f, 0.f, 0.f);
#pragma unroll 8
    for (int j = 0; j < U; ++j) {
        float wj = w_s[j];
        float4 v = p[(size_t)j * TN4];
        acc.x += wj * v.x;
        acc.y += wj * v.y;
        acc.z += wj * v.z;
        acc.w += wj * v.w;
    }

    float4 t = tgt[idx];
    float4 r;
    r.x = acc.x * 0.5f + t.x * 1.5f;
    r.y = acc.y * 0.5f + t.y * 1.5f;
    r.z = acc.z * 0.5f + t.z * 1.5f;
    r.w = acc.w * 0.5f + t.w * 1.5f;
    out[idx] = r;

    // Reductions: sum(final) and sum(input_spikes)
    float4 is = insp[idx];
    float lsum = r.x + r.y + r.z + r.w;
    float lin  = is.x + is.y + is.z + is.w;

#pragma unroll
    for (int off = 32; off > 0; off >>= 1) {
        lsum += __shfl_down(lsum, off, 64);
        lin  += __shfl_down(lin,  off, 64);
    }

    __shared__ float red[8];
    int wave = tid >> 6;
    int lane = tid & 63;
    if (lane == 0) { red[wave] = lsum; red[4 + wave] = lin; }
    __syncthreads();
    if (tid == 0) {
        atomicAdd(&ws[0], red[0] + red[1] + red[2] + red[3]);
        atomicAdd(&ws[1], red[4] + red[5] + red[6] + red[7]);
    }
}

__global__ __launch_bounds__(256) void boost_kernel(const float4* __restrict__ rb,
                                                    float4* __restrict__ out,
                                                    const float* __restrict__ ws) {
    float mean    = ws[0] * (1.0f / TN);
    float in_rate = ws[1] * (1000.0f / TN);     // input_spikes.mean() * 1000
    float target_mean = (in_rate + 20.0f) * 0.01f;
    float boost = fmaxf(0.0f, target_mean - mean);
    if (mean < 0.2f) {
        int idx = blockIdx.x * 256 + threadIdx.x;
        float4 o = out[idx];
        float4 r = rb[idx];
        float b2 = boost * 2.0f;
        o.x += r.x * b2;
        o.y += r.y * b2;
        o.z += r.z * b2;
        o.w += r.w * b2;
        out[idx] = o;
    }
}

extern "C" void kernel_launch(void* const* d_in, const int* in_sizes, int n_in,
                              void* d_out, int out_size, void* d_ws, size_t ws_size,
                              hipStream_t stream) {
    const float* input_spikes = (const float*)d_in[0];   // [T,N]
    const float* unit_outputs = (const float*)d_in[1];   // [U,T,N]
    const float* conn         = (const float*)d_in[2];   // [U,U]
    const float* target       = (const float*)d_in[3];   // [T,N]
    const float* rand_bias    = (const float*)d_in[4];   // [T,N]
    float* out = (float*)d_out;
    float* ws  = (float*)d_ws;

    prep_kernel<<<1, 128, 0, stream>>>(conn, ws);

    main_kernel<<<TN4 / 256, 256, 0, stream>>>(
        (const float4*)unit_outputs,
        (const float4*)target,
        (const float4*)input_spikes,
        (float4*)out, ws);

    boost_kernel<<<TN4 / 256, 256, 0, stream>>>(
        (const float4*)rand_bias, (float4*)out, ws);
}